// Round 13
// baseline (840.566 us; speedup 1.0000x reference)
//
#include <hip/hip_runtime.h>
#include <math.h>

#define DEV static __device__ __forceinline__

typedef unsigned short u16;
typedef __attribute__((ext_vector_type(8))) short short8;
typedef __attribute__((ext_vector_type(4))) float floatx4;

// ---------- helpers ----------
DEV u16 f2bf(float f) {
  unsigned u = __float_as_uint(f);
  unsigned r = u + 0x7FFFu + ((u >> 16) & 1u);
  return (u16)(r >> 16);
}
DEV float bf2f(u16 v) { return __uint_as_float(((unsigned)v) << 16); }

typedef __attribute__((address_space(1))) void gvoid;
typedef __attribute__((address_space(3))) void lvoid;

DEV void gload16(const u16* g, u16* l) {
  __builtin_amdgcn_global_load_lds((gvoid*)g, (lvoid*)l, 16, 0, 0);
}

DEV floatx4 mfma16(short8 a, short8 b, floatx4 c) {
  return __builtin_amdgcn_mfma_f32_16x16x32_bf16(a, b, c, 0, 0, 0);
}

// A-region addressing: row r (0..127) of 512 u16, granule g (=k/8, 0..63),
// swizzle g^(r&7) -> conflict-free ds_read_b128 across 16-lane row groups.
DEV int aidx(int r, int g) { return r * 512 + ((g ^ (r & 7)) << 3); }
// h-region: row r of 64 u16, granule g (0..7), same swizzle.
DEV int hidx(int r, int g) { return (r << 6) + ((g ^ (r & 7)) << 3); }

// ---------- weight convert + transpose: out[n*K+k] = bf16(in[k*N+n]) ----------
__global__ __launch_bounds__(256) void tcast_k(const float* __restrict__ in,
                                               u16* __restrict__ out, int K, int N) {
  __shared__ float t[32][33];
  int nb = blockIdx.x * 32, kb = blockIdx.y * 32;
  int tx = threadIdx.x, ty = threadIdx.y;
#pragma unroll
  for (int r = 0; r < 32; r += 8)
    t[r + ty][tx] = in[(long)(kb + r + ty) * N + nb + tx];
  __syncthreads();
#pragma unroll
  for (int r = 0; r < 32; r += 8)
    out[(long)(nb + r + ty) * K + kb + tx] = f2bf(t[tx][r + ty]);
}

// ---------- fusedA: LN1 + QKV GEMM. one block per (b,a) = 128 rows ----------
// x f32 [M,512] -> xn (bf16 LDS + global) -> qkv = xn @ Wq^T + bq -> qkvB bf16
__global__ __launch_bounds__(512) void fusedA_k(const float* __restrict__ x,
                                                const float* __restrict__ g1,
                                                const float* __restrict__ b1,
                                                const u16* __restrict__ wq,
                                                const float* __restrict__ bq,
                                                u16* __restrict__ xnB,
                                                u16* __restrict__ qkvB) {
  __shared__ __align__(16) u16 as[128 * 512];  // 128 KB
  const int tid = threadIdx.x;
  const int lane = tid & 63, w = tid >> 6;
  const int lane15 = lane & 15, khi = lane >> 4;
  const int wr = w >> 2, wcn = w & 3;  // 2 M-halves x 4 N-quarters
  const long R0 = (long)blockIdx.x * 128;

  // LN1: wave w handles rows w*16 .. +15
  {
    const float4* gp = (const float4*)g1;
    const float4* bp = (const float4*)b1;
    float4 gv0 = gp[lane * 2], gv1 = gp[lane * 2 + 1];
    float4 bv0 = bp[lane * 2], bv1 = bp[lane * 2 + 1];
    float gg[8] = {gv0.x, gv0.y, gv0.z, gv0.w, gv1.x, gv1.y, gv1.z, gv1.w};
    float bb[8] = {bv0.x, bv0.y, bv0.z, bv0.w, bv1.x, bv1.y, bv1.z, bv1.w};
    for (int rr = 0; rr < 16; ++rr) {
      const int r = w * 16 + rr;
      const float4* xr = (const float4*)(x + (R0 + r) * 512);
      float4 v0 = xr[lane * 2], v1 = xr[lane * 2 + 1];
      float vv[8] = {v0.x, v0.y, v0.z, v0.w, v1.x, v1.y, v1.z, v1.w};
      float s = 0.f, q = 0.f;
#pragma unroll
      for (int i = 0; i < 8; ++i) { s += vv[i]; q += vv[i] * vv[i]; }
#pragma unroll
      for (int off = 1; off < 64; off <<= 1) {
        s += __shfl_xor(s, off, 64);
        q += __shfl_xor(q, off, 64);
      }
      float mean = s * (1.f / 512.f);
      float var = q * (1.f / 512.f) - mean * mean;
      float rs = rsqrtf(var + 1e-5f);
      short8 ov;
#pragma unroll
      for (int i = 0; i < 8; ++i)
        ov[i] = (short)f2bf((vv[i] - mean) * rs * gg[i] + bb[i]);
      *(short8*)&xnB[(R0 + r) * 512 + lane * 8] = ov;
      *(short8*)&as[r * 512 + ((lane ^ (r & 7)) << 3)] = ov;
    }
  }
  __syncthreads();

  // QKV: 3 passes of N=512; barrier-free K-loop (A read-only in LDS, B -> VGPR)
  for (int pass = 0; pass < 3; ++pass) {
    const int nb0 = pass * 512 + wcn * 128;
    floatx4 acc[4][8];
#pragma unroll
    for (int mt = 0; mt < 4; ++mt)
#pragma unroll
      for (int nt = 0; nt < 8; ++nt) acc[mt][nt] = floatx4{0.f, 0.f, 0.f, 0.f};
#pragma unroll 2
    for (int ks = 0; ks < 16; ++ks) {
      short8 bfr[8], afr[4];
#pragma unroll
      for (int nt = 0; nt < 8; ++nt)
        bfr[nt] = *(const short8*)&wq[(long)(nb0 + nt * 16 + lane15) * 512 + ks * 32 + khi * 8];
#pragma unroll
      for (int mt = 0; mt < 4; ++mt)
        afr[mt] = *(const short8*)&as[aidx(wr * 64 + mt * 16 + lane15, ks * 4 + khi)];
#pragma unroll
      for (int nt = 0; nt < 8; ++nt)
#pragma unroll
        for (int mt = 0; mt < 4; ++mt)
          acc[mt][nt] = mfma16(afr[mt], bfr[nt], acc[mt][nt]);
    }
#pragma unroll
    for (int mt = 0; mt < 4; ++mt)
#pragma unroll
      for (int nt = 0; nt < 8; ++nt) {
        const int col = nb0 + nt * 16 + lane15;
        const float bv = bq[col];
#pragma unroll
        for (int jj = 0; jj < 4; ++jj) {
          const int row = wr * 64 + mt * 16 + khi * 4 + jj;
          qkvB[(R0 + row) * 1536 + col] = f2bf(acc[mt][nt][jj] + bv);
        }
      }
  }
}

// ---------- fused causal attention, one workgroup per (b,a,h) ----------
__global__ __launch_bounds__(256) void attn_k(const u16* __restrict__ qkv,
                                              u16* __restrict__ y) {
  union U {
    struct { u16 q[128 * 64]; u16 k[128 * 64]; } qk;
    u16 p[128 * 128];
  };
  __shared__ __align__(16) U u;
  __shared__ __align__(16) u16 vt[64 * 128];

  const int tid = threadIdx.x;
  const int lane = tid & 63, wid = tid >> 6;
  const int lane15 = lane & 15, khi = lane >> 4;
  const int h = blockIdx.x & 7;
  const long R0 = (long)(blockIdx.x >> 3) * 128;
  const u16* base = qkv + R0 * 1536 + h * 64;

#pragma unroll
  for (int it = 0; it < 4; ++it) {
    int c = it * 256 + tid;
    int r = c >> 3, ch = c & 7;
    const u16* gq = base + (long)r * 1536 + ch * 8;
    uint4 dq = *(const uint4*)gq;
    uint4 dk = *(const uint4*)(gq + 512);
    uint4 dv = *(const uint4*)(gq + 1024);
    int qi = (r * 64 + ch * 8) ^ ((r & 7) << 3);
    *(uint4*)&u.qk.q[qi] = dq;
    *(uint4*)&u.qk.k[qi] = dk;
    u16 tmp[8];
    *(uint4*)tmp = dv;
#pragma unroll
    for (int i = 0; i < 8; ++i) {
      int d = ch * 8 + i;
      vt[(d * 128 + r) ^ ((d & 7) << 3)] = tmp[i];
    }
  }
  __syncthreads();

  const int r0 = wid * 32;
  floatx4 sc[2][8];
#pragma unroll
  for (int mt = 0; mt < 2; ++mt)
#pragma unroll
    for (int c = 0; c < 8; ++c) sc[mt][c] = floatx4{0.f, 0.f, 0.f, 0.f};

#pragma unroll
  for (int kk = 0; kk < 2; ++kk) {
    short8 aq[2];
#pragma unroll
    for (int mt = 0; mt < 2; ++mt) {
      int rr = r0 + mt * 16 + lane15;
      aq[mt] = *(const short8*)&u.qk.q[(rr * 64 + kk * 32 + khi * 8) ^ ((rr & 7) << 3)];
    }
#pragma unroll
    for (int c = 0; c < 8; ++c) {
      int rk = c * 16 + lane15;
      short8 bk = *(const short8*)&u.qk.k[(rk * 64 + kk * 32 + khi * 8) ^ ((rk & 7) << 3)];
#pragma unroll
      for (int mt = 0; mt < 2; ++mt)
        sc[mt][c] = mfma16(aq[mt], bk, sc[mt][c]);
    }
  }
  __syncthreads();

#pragma unroll
  for (int mt = 0; mt < 2; ++mt) {
#pragma unroll
    for (int jj = 0; jj < 4; ++jj) {
      int t = r0 + mt * 16 + khi * 4 + jj;
      float vals[8];
      float mx = -1e30f;
#pragma unroll
      for (int c = 0; c < 8; ++c) {
        int s = c * 16 + lane15;
        float v = sc[mt][c][jj] * 0.125f;
        vals[c] = (s <= t) ? v : -1e30f;
        mx = fmaxf(mx, vals[c]);
      }
#pragma unroll
      for (int off = 1; off < 16; off <<= 1) mx = fmaxf(mx, __shfl_xor(mx, off, 64));
      float sum = 0.f;
#pragma unroll
      for (int c = 0; c < 8; ++c) {
        float p = __expf(vals[c] - mx);
        vals[c] = p;
        sum += p;
      }
#pragma unroll
      for (int off = 1; off < 16; off <<= 1) sum += __shfl_xor(sum, off, 64);
      float inv = 1.f / sum;
#pragma unroll
      for (int c = 0; c < 8; ++c) {
        int s = c * 16 + lane15;
        u.p[(t * 128 + s) ^ ((t & 7) << 3)] = f2bf(vals[c] * inv);
      }
    }
  }
  __syncthreads();

  floatx4 ya[2][4];
#pragma unroll
  for (int mt = 0; mt < 2; ++mt)
#pragma unroll
    for (int n = 0; n < 4; ++n) ya[mt][n] = floatx4{0.f, 0.f, 0.f, 0.f};

#pragma unroll
  for (int kk = 0; kk < 4; ++kk) {
    short8 ap[2];
#pragma unroll
    for (int mt = 0; mt < 2; ++mt) {
      int rr = r0 + mt * 16 + lane15;
      ap[mt] = *(const short8*)&u.p[(rr * 128 + kk * 32 + khi * 8) ^ ((rr & 7) << 3)];
    }
#pragma unroll
    for (int n = 0; n < 4; ++n) {
      int d = n * 16 + lane15;
      short8 bv = *(const short8*)&vt[(d * 128 + kk * 32 + khi * 8) ^ ((d & 7) << 3)];
#pragma unroll
      for (int mt = 0; mt < 2; ++mt)
        ya[mt][n] = mfma16(ap[mt], bv, ya[mt][n]);
    }
  }

  u16* yb = y + R0 * 512 + h * 64;
#pragma unroll
  for (int mt = 0; mt < 2; ++mt)
#pragma unroll
    for (int n = 0; n < 4; ++n)
#pragma unroll
      for (int jj = 0; jj < 4; ++jj) {
        int t = r0 + mt * 16 + khi * 4 + jj;
        int d = n * 16 + lane15;
        yb[(long)t * 512 + d] = f2bf(ya[mt][n][jj]);
      }
}

// ---------- fusedB: proj(+xn res) -> LN2 -> FC+gelu -> OUT(+xn2 res) ----------
// one block per (b,a). LDS: as 128KB (ys -> x2 -> xn2) + hs 16KB (h chunk).
__global__ __launch_bounds__(512) void fusedB_k(const u16* __restrict__ yB,
                                                const u16* __restrict__ xnB,
                                                const u16* __restrict__ wp,
                                                const float* __restrict__ bp,
                                                const float* __restrict__ g2,
                                                const float* __restrict__ b2,
                                                const u16* __restrict__ wf,
                                                const float* __restrict__ bfc,
                                                const u16* __restrict__ wo,
                                                const float* __restrict__ bo,
                                                float* __restrict__ out) {
  __shared__ __align__(16) u16 as[128 * 512];  // 128 KB
  __shared__ __align__(16) u16 hs[128 * 64];   // 16 KB
  const int tid = threadIdx.x;
  const int lane = tid & 63, w = tid >> 6;
  const int lane15 = lane & 15, khi = lane >> 4;
  const int wr = w >> 2, wcn = w & 3;
  const long R0 = (long)blockIdx.x * 128;

  // stage ys -> as (linear dest, pre-swizzled source; one row per gload call)
  for (int rr = 0; rr < 16; ++rr) {
    const int r = w * 16 + rr;
    gload16(yB + (R0 + r) * 512 + ((lane ^ (r & 7)) << 3), &as[r * 512]);
  }
  asm volatile("s_waitcnt vmcnt(0)" ::: "memory");
  __syncthreads();

  floatx4 acc[4][8];
#pragma unroll
  for (int mt = 0; mt < 4; ++mt)
#pragma unroll
    for (int nt = 0; nt < 8; ++nt) acc[mt][nt] = floatx4{0.f, 0.f, 0.f, 0.f};

  // proj: x2 = y @ Wp^T (barrier-free K-loop)
#pragma unroll 2
  for (int ks = 0; ks < 16; ++ks) {
    short8 bfr[8], afr[4];
#pragma unroll
    for (int nt = 0; nt < 8; ++nt)
      bfr[nt] = *(const short8*)&wp[(long)(wcn * 128 + nt * 16 + lane15) * 512 + ks * 32 + khi * 8];
#pragma unroll
    for (int mt = 0; mt < 4; ++mt)
      afr[mt] = *(const short8*)&as[aidx(wr * 64 + mt * 16 + lane15, ks * 4 + khi)];
#pragma unroll
    for (int nt = 0; nt < 8; ++nt)
#pragma unroll
      for (int mt = 0; mt < 4; ++mt)
        acc[mt][nt] = mfma16(afr[mt], bfr[nt], acc[mt][nt]);
  }
  __syncthreads();  // all ys reads done before overwriting as with x2

  // x2 = acc + bp + xn  -> as (bf16, swizzled)
#pragma unroll
  for (int mt = 0; mt < 4; ++mt)
#pragma unroll
    for (int nt = 0; nt < 8; ++nt) {
      const int col = wcn * 128 + nt * 16 + lane15;
      const float bv = bp[col];
#pragma unroll
      for (int jj = 0; jj < 4; ++jj) {
        const int row = wr * 64 + mt * 16 + khi * 4 + jj;
        float v = acc[mt][nt][jj] + bv + bf2f(xnB[(R0 + row) * 512 + col]);
        as[row * 512 + (((col >> 3) ^ (row & 7)) << 3) + (col & 7)] = f2bf(v);
      }
    }
  __syncthreads();

  // LN2 in place: wave per row x16
  {
    const float4* gp = (const float4*)g2;
    const float4* bpx = (const float4*)b2;
    float4 gv0 = gp[lane * 2], gv1 = gp[lane * 2 + 1];
    float4 bv0 = bpx[lane * 2], bv1 = bpx[lane * 2 + 1];
    float gg[8] = {gv0.x, gv0.y, gv0.z, gv0.w, gv1.x, gv1.y, gv1.z, gv1.w};
    float bb[8] = {bv0.x, bv0.y, bv0.z, bv0.w, bv1.x, bv1.y, bv1.z, bv1.w};
    for (int rr = 0; rr < 16; ++rr) {
      const int r = w * 16 + rr;
      const int idx = r * 512 + ((lane ^ (r & 7)) << 3);
      short8 v = *(const short8*)&as[idx];
      float vv[8];
#pragma unroll
      for (int i = 0; i < 8; ++i) vv[i] = bf2f((u16)v[i]);
      float s = 0.f, q = 0.f;
#pragma unroll
      for (int i = 0; i < 8; ++i) { s += vv[i]; q += vv[i] * vv[i]; }
#pragma unroll
      for (int off = 1; off < 64; off <<= 1) {
        s += __shfl_xor(s, off, 64);
        q += __shfl_xor(q, off, 64);
      }
      float mean = s * (1.f / 512.f);
      float var = q * (1.f / 512.f) - mean * mean;
      float rs = rsqrtf(var + 1e-5f);
      short8 ov;
#pragma unroll
      for (int i = 0; i < 8; ++i)
        ov[i] = (short)f2bf((vv[i] - mean) * rs * gg[i] + bb[i]);
      *(short8*)&as[idx] = ov;
    }
  }
  __syncthreads();

  // MLP: out_acc (reuse acc) accumulates over 32 h-chunks of 64 cols
#pragma unroll
  for (int mt = 0; mt < 4; ++mt)
#pragma unroll
    for (int nt = 0; nt < 8; ++nt) acc[mt][nt] = floatx4{0.f, 0.f, 0.f, 0.f};

  for (int c = 0; c < 32; ++c) {
    // FC: h chunk cols c*64..+63; wave owns 64 rows x 16 cols
    const int hn0 = c * 64 + wcn * 16;
    floatx4 hacc[4];
#pragma unroll
    for (int mt = 0; mt < 4; ++mt) hacc[mt] = floatx4{0.f, 0.f, 0.f, 0.f};
#pragma unroll 4
    for (int ks = 0; ks < 16; ++ks) {
      short8 bfr = *(const short8*)&wf[(long)(hn0 + lane15) * 512 + ks * 32 + khi * 8];
#pragma unroll
      for (int mt = 0; mt < 4; ++mt) {
        short8 afr = *(const short8*)&as[aidx(wr * 64 + mt * 16 + lane15, ks * 4 + khi)];
        hacc[mt] = mfma16(afr, bfr, hacc[mt]);
      }
    }
    __syncthreads();  // previous chunk's OUT reads of hs complete
    // gelu -> hs (bf16, swizzled)
#pragma unroll
    for (int mt = 0; mt < 4; ++mt) {
      const int ccol = wcn * 16 + lane15;
      const float bv = bfc[c * 64 + ccol];
#pragma unroll
      for (int jj = 0; jj < 4; ++jj) {
        const int row = wr * 64 + mt * 16 + khi * 4 + jj;
        float v = hacc[mt][jj] + bv;
        v = 0.5f * v * (1.f + erff(v * 0.70710678118f));
        hs[(row << 6) + (((ccol >> 3) ^ (row & 7)) << 3) + (ccol & 7)] = f2bf(v);
      }
    }
    __syncthreads();
    // OUT accumulation: K-chunk = 64 (2 k-steps), A = hs, B = Wout^T rows
#pragma unroll
    for (int ks2 = 0; ks2 < 2; ++ks2) {
      short8 bfr[8], afr[4];
#pragma unroll
      for (int nt = 0; nt < 8; ++nt)
        bfr[nt] = *(const short8*)&wo[(long)(wcn * 128 + nt * 16 + lane15) * 2048 + c * 64 + ks2 * 32 + khi * 8];
#pragma unroll
      for (int mt = 0; mt < 4; ++mt)
        afr[mt] = *(const short8*)&hs[hidx(wr * 64 + mt * 16 + lane15, ks2 * 4 + khi)];
#pragma unroll
      for (int nt = 0; nt < 8; ++nt)
#pragma unroll
        for (int mt = 0; mt < 4; ++mt)
          acc[mt][nt] = mfma16(afr[mt], bfr[nt], acc[mt][nt]);
    }
  }

  // final: out = acc + bo + xn2 (f32)
#pragma unroll
  for (int mt = 0; mt < 4; ++mt)
#pragma unroll
    for (int nt = 0; nt < 8; ++nt) {
      const int col = wcn * 128 + nt * 16 + lane15;
      const float bv = bo[col];
#pragma unroll
      for (int jj = 0; jj < 4; ++jj) {
        const int row = wr * 64 + mt * 16 + khi * 4 + jj;
        float xn2 = bf2f(as[row * 512 + (((col >> 3) ^ (row & 7)) << 3) + (col & 7)]);
        out[(R0 + row) * 512 + col] = acc[mt][nt][jj] + bv + xn2;
      }
    }
}

// ---------- launch ----------
// ws: [0,6M) weights; [8M,40M) xnB; [40M,136M) qkvB; [136M,168M) yB. Peak 168 MiB.
extern "C" void kernel_launch(void* const* d_in, const int* in_sizes, int n_in,
                              void* d_out, int out_size, void* d_ws, size_t ws_size,
                              hipStream_t stream) {
  const float* x      = (const float*)d_in[0];
  const float* ln1_g  = (const float*)d_in[1];
  const float* ln1_b  = (const float*)d_in[2];
  const float* W_qkv  = (const float*)d_in[3];
  const float* b_qkv  = (const float*)d_in[4];
  const float* W_proj = (const float*)d_in[5];
  const float* b_proj = (const float*)d_in[6];
  const float* ln2_g  = (const float*)d_in[7];
  const float* ln2_b  = (const float*)d_in[8];
  const float* W_fc   = (const float*)d_in[9];
  const float* b_fc   = (const float*)d_in[10];
  const float* W_out  = (const float*)d_in[11];
  const float* b_out  = (const float*)d_in[12];

  const size_t MiB = 1024 * 1024;
  char* ws = (char*)d_ws;
  u16* wq   = (u16*)(ws + 0);
  u16* wp   = (u16*)(ws + 1536 * 512 * 2);
  u16* wf   = (u16*)(ws + 2 * MiB);
  u16* wo   = (u16*)(ws + 4 * MiB);
  u16* xnB  = (u16*)(ws + 8 * MiB);
  u16* qkvB = (u16*)(ws + 40 * MiB);
  u16* yB   = (u16*)(ws + 136 * MiB);

  tcast_k<<<dim3(1536 / 32, 512 / 32), dim3(32, 8), 0, stream>>>(W_qkv, wq, 512, 1536);
  tcast_k<<<dim3(512 / 32, 512 / 32), dim3(32, 8), 0, stream>>>(W_proj, wp, 512, 512);
  tcast_k<<<dim3(2048 / 32, 512 / 32), dim3(32, 8), 0, stream>>>(W_fc, wf, 512, 2048);
  tcast_k<<<dim3(512 / 32, 2048 / 32), dim3(32, 8), 0, stream>>>(W_out, wo, 2048, 512);

  // LN1 + QKV
  fusedA_k<<<256, 512, 0, stream>>>(x, ln1_g, ln1_b, wq, b_qkv, xnB, qkvB);
  // attention
  attn_k<<<2048, 256, 0, stream>>>(qkvB, yB);
  // proj + res -> LN2 -> FC + gelu -> OUT + res
  fusedB_k<<<256, 512, 0, stream>>>(yB, xnB, wp, b_proj, ln2_g, ln2_b,
                                    wf, b_fc, wo, b_out, (float*)d_out);
}